// Round 2
// baseline (70278.925 us; speedup 1.0000x reference)
//
#include <hip/hip_runtime.h>

// RNN: s_{t+1} = 0.9*s + 0.1*(relu(s@Wrec^T + (u+inz)@Winp^T) + rn)
// d_out = states (B,T,N) fp32 then outputs (B,T,1) fp32, flat-concat.
//
// Structure: batch chains are independent -> no grid sync. 64 WGs x 1024
// threads, 2 batches/WG (G=2 balances per-XCD L2 W-traffic ~1.85us/step
// against per-CU VALU ~1.7us/step). Wrec pre-transposed (Wt[k][n]) for
// coalesced float4 loads. Phase A: thread (n4, kc) accumulates 4 n's over a
// 64-wide k-chunk, W double-buffered in registers 8 float4 ahead (W addrs
// are t-invariant, so blk7 prefetches next step's blk0 across the barriers).
// Phase B: thread = (batch, n); LDS reduce over 8 k-chunks; fused W_out dot.

#define NN 512
#define BB 128
#define TT 1000
#define NIN 6
#define KL 64   // k per chunk (8 chunks)
#define PB 8    // W prefetch block (float4s)

__global__ void transpose_w(const float* __restrict__ W, float* __restrict__ Wt) {
  __shared__ float tile[32][33];
  const int bx = blockIdx.x * 32, by = blockIdx.y * 32;
  const int tx = threadIdx.x, ty = threadIdx.y;  // 32 x 8
  #pragma unroll
  for (int i = ty; i < 32; i += 8)
    tile[i][tx] = W[(size_t)(by + i) * NN + bx + tx];
  __syncthreads();
  #pragma unroll
  for (int i = ty; i < 32; i += 8)
    Wt[(size_t)(bx + i) * NN + by + tx] = tile[tx][i];
}

__device__ __forceinline__ float wave_sum(float v) {
  #pragma unroll
  for (int off = 32; off > 0; off >>= 1) v += __shfl_xor(v, off, 64);
  return v;
}

template <bool TRANS>
__device__ __forceinline__ void loadw(float4* dst, const float* wp, int kbase) {
  #pragma unroll
  for (int j = 0; j < PB; ++j) {
    if (TRANS) {
      dst[j] = *reinterpret_cast<const float4*>(wp + (size_t)(kbase + j) * NN);
    } else {
      const float* p = wp + kbase + j;
      dst[j].x = p[0]; dst[j].y = p[NN]; dst[j].z = p[2 * NN]; dst[j].w = p[3 * NN];
    }
  }
}

template <bool TRANS>
__global__ __launch_bounds__(1024, 4)
void rnn_fused(const float* __restrict__ u, const float* __restrict__ rnz,
               const float* __restrict__ inz, const float* __restrict__ Wsrc,
               const float* __restrict__ Winp, const float* __restrict__ Wout,
               const float* __restrict__ yinit,
               float* __restrict__ states, float* __restrict__ outputs) {
  const int tid = threadIdx.x;
  const int n4 = tid & 127;   // phase-A n-group (4 n's)
  const int kc = tid >> 7;    // phase-A k-chunk 0..7 (wave-uniform)
  const int b0 = blockIdx.x * 2;
  const int n  = tid & 511;   // phase-B neuron
  const int pb = tid >> 9;    // phase-B batch select (0/1)
  const int bb = b0 + pb;

  __shared__ __align__(16) float s[2][NN];          // 4 KB
  __shared__ __align__(16) float red[2][128][36];   // 8 chunks*4 + pad4: 36.9 KB
  __shared__ float ubuf[2 * NIN];
  __shared__ float outred[2][8];

  float wi[NIN];
  #pragma unroll
  for (int j = 0; j < NIN; ++j) wi[j] = Winp[n * NIN + j];
  const float wo = Wout[n];
  const float yv = yinit[n];

  const float* rp = rnz + (size_t)bb * TT * NN + n;     // rn for (bb, n)
  float* sp = states + (size_t)bb * TT * NN + n;

  // t = 0
  if (tid < NN) { s[0][tid] = yv; s[1][tid] = yv; }
  sp[0] = yv;
  float scur = yv;
  {
    float p = wave_sum(yv * wo);
    if ((tid & 63) == 0) outred[pb][(tid >> 6) & 7] = p;
  }
  __syncthreads();
  if ((tid & 511) == 0) {
    float a = 0.f;
    #pragma unroll
    for (int w = 0; w < 8; ++w) a += outred[pb][w];
    outputs[bb * TT] = a;
  }
  // safe without extra barrier: next write to outred is after sync #1 below,
  // which the reading thread must also reach.

  const float* wp = TRANS ? (Wsrc + (size_t)(kc * KL) * NN + (n4 << 2))
                          : (Wsrc + (size_t)(n4 << 2) * NN + kc * KL);

  float4 wreg0[PB], wreg1[PB];
  loadw<TRANS>(wreg0, wp, 0);  // prologue: block 0 in flight

  for (int t = 0; t < TT - 1; ++t) {
    // per-step global loads issued early, hidden under the k-loop
    const float rn = rp[(size_t)t * NN];
    float uv = 0.f;
    if (tid < 2 * NIN) {
      const int ib = b0 + (tid >= NIN);
      const int j = (tid < NIN) ? tid : tid - NIN;
      const int idx = (ib * TT + t) * NIN + j;
      uv = u[idx] + inz[idx];
    }

    // ---- phase A: partial matvec over this thread's 64-wide k-chunk ----
    float a0[4] = {0.f, 0.f, 0.f, 0.f};
    float a1[4] = {0.f, 0.f, 0.f, 0.f};
    #pragma unroll
    for (int blk = 0; blk < KL / PB; ++blk) {  // 8 blocks, static indices
      float4* curw = (blk & 1) ? wreg1 : wreg0;
      float4* nxtw = (blk & 1) ? wreg0 : wreg1;
      // prefetch next block; blk7 prefetches NEXT STEP's block 0 (W is
      // t-invariant) so its latency hides under phase B + both barriers.
      loadw<TRANS>(nxtw, wp, (blk == KL / PB - 1) ? 0 : (blk + 1) * PB);

      const int k0 = kc * KL + blk * PB;
      float s0v[PB], s1v[PB];
      #pragma unroll
      for (int q = 0; q < PB / 4; ++q) {  // broadcast LDS reads (wave-uniform)
        const float4 t0 = *reinterpret_cast<const float4*>(&s[0][k0 + 4 * q]);
        const float4 t1 = *reinterpret_cast<const float4*>(&s[1][k0 + 4 * q]);
        s0v[4*q+0] = t0.x; s0v[4*q+1] = t0.y; s0v[4*q+2] = t0.z; s0v[4*q+3] = t0.w;
        s1v[4*q+0] = t1.x; s1v[4*q+1] = t1.y; s1v[4*q+2] = t1.z; s1v[4*q+3] = t1.w;
      }
      #pragma unroll
      for (int j = 0; j < PB; ++j) {
        const float4 w = curw[j];
        a0[0] = fmaf(w.x, s0v[j], a0[0]);
        a0[1] = fmaf(w.y, s0v[j], a0[1]);
        a0[2] = fmaf(w.z, s0v[j], a0[2]);
        a0[3] = fmaf(w.w, s0v[j], a0[3]);
        a1[0] = fmaf(w.x, s1v[j], a1[0]);
        a1[1] = fmaf(w.y, s1v[j], a1[1]);
        a1[2] = fmaf(w.z, s1v[j], a1[2]);
        a1[3] = fmaf(w.w, s1v[j], a1[3]);
      }
    }
    if (tid < 2 * NIN) ubuf[tid] = uv;
    *reinterpret_cast<float4*>(&red[0][n4][kc << 2]) =
        make_float4(a0[0], a0[1], a0[2], a0[3]);
    *reinterpret_cast<float4*>(&red[1][n4][kc << 2]) =
        make_float4(a1[0], a1[1], a1[2], a1[3]);
    __syncthreads();  // #1: red + ubuf visible

    // ---- phase B: finalize (bb, n) ----
    const int r = n >> 2, c = n & 3;
    float pre = 0.f;
    #pragma unroll
    for (int q = 0; q < 8; ++q) pre += red[pb][r][(q << 2) + c];
    #pragma unroll
    for (int j = 0; j < NIN; ++j) pre = fmaf(ubuf[pb * NIN + j], wi[j], pre);
    const float sn = 0.9f * scur + 0.1f * (fmaxf(pre, 0.f) + rn);
    sp[(size_t)(t + 1) * NN] = sn;
    s[pb][n] = sn;   // must land before sync #2 (next k-loop reads all of s)
    scur = sn;
    float p = wave_sum(sn * wo);
    if ((tid & 63) == 0) outred[pb][(tid >> 6) & 7] = p;
    __syncthreads();  // #2: s + outred visible; red safe to overwrite
    if ((tid & 511) == 0) {
      float a = 0.f;
      #pragma unroll
      for (int w = 0; w < 8; ++w) a += outred[pb][w];
      outputs[bb * TT + t + 1] = a;
    }
  }
}

extern "C" void kernel_launch(void* const* d_in, const int* in_sizes, int n_in,
                              void* d_out, int out_size, void* d_ws, size_t ws_size,
                              hipStream_t stream) {
  const float* u    = (const float*)d_in[0];
  const float* rnz  = (const float*)d_in[1];
  const float* inz  = (const float*)d_in[2];
  const float* Wrec = (const float*)d_in[3];
  const float* Winp = (const float*)d_in[4];
  const float* Wout = (const float*)d_in[5];
  const float* yin  = (const float*)d_in[6];
  float* states  = (float*)d_out;
  float* outputs = states + (size_t)BB * TT * NN;

  const bool use_t = ws_size >= (size_t)NN * NN * sizeof(float);
  if (use_t) {
    float* Wt = (float*)d_ws;
    transpose_w<<<dim3(16, 16), dim3(32, 8), 0, stream>>>(Wrec, Wt);
    rnn_fused<true><<<BB / 2, 1024, 0, stream>>>(u, rnz, inz, Wt, Winp, Wout,
                                                 yin, states, outputs);
  } else {
    rnn_fused<false><<<BB / 2, 1024, 0, stream>>>(u, rnz, inz, Wrec, Winp, Wout,
                                                  yin, states, outputs);
  }
}

// Round 4
// 66851.349 us; speedup vs baseline: 1.0513x; 1.0513x over previous
//
#include <hip/hip_runtime.h>

// RNN: s_{t+1} = 0.9*s + 0.1*(relu(s@Wrec^T + (u+inz)@Winp^T) + rn)
// d_out = states (B,T,N) fp32 then outputs (B,T,1) fp32, flat-concat.
//
// 64 WGs x 1024 threads, 2 batches/WG (G=2 balances per-XCD L2 W traffic
// ~1.86us/step vs per-CU VALU floor ~1.71us/step). Wrec pre-transposed
// Wt[k][n]. Phase A: thread (n4, kc) owns 4 n's over a 64-wide k-chunk;
// W register-double-buffered as structs of NAMED float4 members (R2's
// pointer-swapped arrays were demoted to scratch -> 77GB spill traffic;
// R3's macro member names collided with header macros -> inline fns now).
// Pipeline: stage j consumes k-block j, reloads that buffer with block
// j+2 (mod 16, wrapping into next t: W addrs are t-invariant), so 2
// blocks are always in flight, incl. across both barriers.
// Phase B: thread = (batch, n); LDS reduce over 8 k-chunks; fused Wout dot.

#define NN 512
#define BB 128
#define TT 1000
#define NIN 6

__global__ void transpose_w(const float* __restrict__ W, float* __restrict__ Wt) {
  __shared__ float tile[32][33];
  const int bx = blockIdx.x * 32, by = blockIdx.y * 32;
  const int tx = threadIdx.x, ty = threadIdx.y;  // 32 x 8
  #pragma unroll
  for (int i = ty; i < 32; i += 8)
    tile[i][tx] = W[(size_t)(by + i) * NN + bx + tx];
  __syncthreads();
  #pragma unroll
  for (int i = ty; i < 32; i += 8)
    Wt[(size_t)(bx + i) * NN + by + tx] = tile[tx][i];
}

__device__ __forceinline__ float wave_sum(float v) {
  #pragma unroll
  for (int off = 32; off > 0; off >>= 1) v += __shfl_xor(v, off, 64);
  return v;
}

// 4 k-rows x 4 n-cols of W, named members (register-resident).
struct W4 {
  float4 e0_, e1_, e2_, e3_;
};

template <bool TRANS>
__device__ __forceinline__ W4 loadw4(const float* __restrict__ wp, int kbase) {
  W4 r;
  if (TRANS) {
    const float* p = wp + (size_t)kbase * NN;  // Wt[k][n]: row k, 4 n's
    r.e0_ = *reinterpret_cast<const float4*>(p);
    r.e1_ = *reinterpret_cast<const float4*>(p + NN);
    r.e2_ = *reinterpret_cast<const float4*>(p + 2 * NN);
    r.e3_ = *reinterpret_cast<const float4*>(p + 3 * NN);
  } else {
    const float* p = wp + kbase;  // W[n][k]: gather 4 n's per k (slow path)
    r.e0_.x = p[0*NN+0]; r.e0_.y = p[1*NN+0]; r.e0_.z = p[2*NN+0]; r.e0_.w = p[3*NN+0];
    r.e1_.x = p[0*NN+1]; r.e1_.y = p[1*NN+1]; r.e1_.z = p[2*NN+1]; r.e1_.w = p[3*NN+1];
    r.e2_.x = p[0*NN+2]; r.e2_.y = p[1*NN+2]; r.e2_.z = p[2*NN+2]; r.e2_.w = p[3*NN+2];
    r.e3_.x = p[0*NN+3]; r.e3_.y = p[1*NN+3]; r.e3_.z = p[2*NN+3]; r.e3_.w = p[3*NN+3];
  }
  return r;
}

__device__ __forceinline__ void fma4(float4& a, const float4 w, const float sv) {
  a.x = fmaf(w.x, sv, a.x);
  a.y = fmaf(w.y, sv, a.y);
  a.z = fmaf(w.z, sv, a.z);
  a.w = fmaf(w.w, sv, a.w);
}

// consume one W4 (k..k+3 x 4 n's) against both batches' s broadcasts
__device__ __forceinline__ void consume4(const W4& w4, const float* sp0,
                                         const float* sp1, float4& a0, float4& a1) {
  const float4 s0v = *reinterpret_cast<const float4*>(sp0);
  const float4 s1v = *reinterpret_cast<const float4*>(sp1);
  fma4(a0, w4.e0_, s0v.x); fma4(a1, w4.e0_, s1v.x);
  fma4(a0, w4.e1_, s0v.y); fma4(a1, w4.e1_, s1v.y);
  fma4(a0, w4.e2_, s0v.z); fma4(a1, w4.e2_, s1v.z);
  fma4(a0, w4.e3_, s0v.w); fma4(a1, w4.e3_, s1v.w);
}

template <bool TRANS>
__global__ __launch_bounds__(1024, 4)
void rnn_fused(const float* __restrict__ u, const float* __restrict__ rnz,
               const float* __restrict__ inz, const float* __restrict__ Wsrc,
               const float* __restrict__ Winp, const float* __restrict__ Wout,
               const float* __restrict__ yinit,
               float* __restrict__ states, float* __restrict__ outputs) {
  const int tid = threadIdx.x;
  const int n4 = tid & 127;     // phase-A n-group (4 n's), varies per lane
  const int n0 = n4 << 2;
  const int kc = tid >> 7;      // phase-A k-chunk 0..7 (wave-uniform)
  const int kchunk = kc << 6;   // k base (64 wide)
  const int b0 = blockIdx.x * 2;
  const int n  = tid & 511;     // phase-B neuron
  const int pb = tid >> 9;      // phase-B batch select
  const int bb = b0 + pb;

  __shared__ __align__(16) float s[2][NN];       // 4 KB
  __shared__ __align__(16) float red[2][8][NN];  // 32 KB, [b][kc][n]
  __shared__ float ubuf[2 * NIN];
  __shared__ float outred[2][8];

  float wi[NIN];
  #pragma unroll
  for (int j = 0; j < NIN; ++j) wi[j] = Winp[n * NIN + j];
  const float wo = Wout[n];
  const float yv = yinit[n];

  const float* rp = rnz + (size_t)bb * TT * NN + n;
  float* sp = states + (size_t)bb * TT * NN + n;

  // t = 0
  if (tid < NN) { s[0][tid] = yv; s[1][tid] = yv; }
  sp[0] = yv;
  float scur = yv;
  {
    float p = wave_sum(yv * wo);
    if ((tid & 63) == 0) outred[pb][(tid >> 6) & 7] = p;
  }
  __syncthreads();
  if ((tid & 511) == 0) {
    float a = 0.f;
    #pragma unroll
    for (int w = 0; w < 8; ++w) a += outred[pb][w];
    outputs[bb * TT] = a;
  }
  // next outred write is after sync #1 below -> no race with the read above

  const float* wp = TRANS ? (Wsrc + (size_t)kchunk * NN + n0)
                          : (Wsrc + (size_t)n0 * NN + kchunk);

  // prologue: k-blocks 0 and 1 in flight
  W4 wA = loadw4<TRANS>(wp, 0);
  W4 wB = loadw4<TRANS>(wp, 4);

  for (int t = 0; t < TT - 1; ++t) {
    const float rn = rp[(size_t)t * NN];  // issued early, used in phase B
    float uv = 0.f;
    if (tid < 2 * NIN) {
      const int ib = b0 + (tid >= NIN);
      const int j = (tid < NIN) ? tid : tid - NIN;
      const int idx = (ib * TT + t) * NIN + j;
      uv = u[idx] + inz[idx];
    }

    // ---- phase A: 64-wide k-chunk, depth-2 register pipeline ----
    float4 acc0 = make_float4(0.f, 0.f, 0.f, 0.f);
    float4 acc1 = acc0;
    const float* s0 = &s[0][kchunk];
    const float* s1 = &s[1][kchunk];
    consume4(wA, s0 +  0, s1 +  0, acc0, acc1); wA = loadw4<TRANS>(wp,  8);
    consume4(wB, s0 +  4, s1 +  4, acc0, acc1); wB = loadw4<TRANS>(wp, 12);
    consume4(wA, s0 +  8, s1 +  8, acc0, acc1); wA = loadw4<TRANS>(wp, 16);
    consume4(wB, s0 + 12, s1 + 12, acc0, acc1); wB = loadw4<TRANS>(wp, 20);
    consume4(wA, s0 + 16, s1 + 16, acc0, acc1); wA = loadw4<TRANS>(wp, 24);
    consume4(wB, s0 + 20, s1 + 20, acc0, acc1); wB = loadw4<TRANS>(wp, 28);
    consume4(wA, s0 + 24, s1 + 24, acc0, acc1); wA = loadw4<TRANS>(wp, 32);
    consume4(wB, s0 + 28, s1 + 28, acc0, acc1); wB = loadw4<TRANS>(wp, 36);
    consume4(wA, s0 + 32, s1 + 32, acc0, acc1); wA = loadw4<TRANS>(wp, 40);
    consume4(wB, s0 + 36, s1 + 36, acc0, acc1); wB = loadw4<TRANS>(wp, 44);
    consume4(wA, s0 + 40, s1 + 40, acc0, acc1); wA = loadw4<TRANS>(wp, 48);
    consume4(wB, s0 + 44, s1 + 44, acc0, acc1); wB = loadw4<TRANS>(wp, 52);
    consume4(wA, s0 + 48, s1 + 48, acc0, acc1); wA = loadw4<TRANS>(wp, 56);
    consume4(wB, s0 + 52, s1 + 52, acc0, acc1); wB = loadw4<TRANS>(wp, 60);
    consume4(wA, s0 + 56, s1 + 56, acc0, acc1); wA = loadw4<TRANS>(wp,  0);
    consume4(wB, s0 + 60, s1 + 60, acc0, acc1); wB = loadw4<TRANS>(wp,  4);
    // wA/wB now hold next step's blocks 0/1 -> latency hidden across barriers

    if (tid < 2 * NIN) ubuf[tid] = uv;
    *reinterpret_cast<float4*>(&red[0][kc][n0]) = acc0;
    *reinterpret_cast<float4*>(&red[1][kc][n0]) = acc1;
    __syncthreads();  // #1: red + ubuf visible

    // ---- phase B: finalize (bb, n) ----
    float pre = 0.f;
    #pragma unroll
    for (int q = 0; q < 8; ++q) pre += red[pb][q][n];
    #pragma unroll
    for (int j = 0; j < NIN; ++j) pre = fmaf(ubuf[pb * NIN + j], wi[j], pre);
    const float sn = 0.9f * scur + 0.1f * (fmaxf(pre, 0.f) + rn);
    sp[(size_t)(t + 1) * NN] = sn;
    s[pb][n] = sn;
    scur = sn;
    float p = wave_sum(sn * wo);
    if ((tid & 63) == 0) outred[pb][(tid >> 6) & 7] = p;
    __syncthreads();  // #2: s + outred visible; red safe to overwrite
    if ((tid & 511) == 0) {
      float a = 0.f;
      #pragma unroll
      for (int w = 0; w < 8; ++w) a += outred[pb][w];
      outputs[bb * TT + t + 1] = a;
    }
  }
}

extern "C" void kernel_launch(void* const* d_in, const int* in_sizes, int n_in,
                              void* d_out, int out_size, void* d_ws, size_t ws_size,
                              hipStream_t stream) {
  const float* u    = (const float*)d_in[0];
  const float* rnz  = (const float*)d_in[1];
  const float* inz  = (const float*)d_in[2];
  const float* Wrec = (const float*)d_in[3];
  const float* Winp = (const float*)d_in[4];
  const float* Wout = (const float*)d_in[5];
  const float* yin  = (const float*)d_in[6];
  float* states  = (float*)d_out;
  float* outputs = states + (size_t)BB * TT * NN;

  const bool use_t = ws_size >= (size_t)NN * NN * sizeof(float);
  if (use_t) {
    float* Wt = (float*)d_ws;
    transpose_w<<<dim3(16, 16), dim3(32, 8), 0, stream>>>(Wrec, Wt);
    rnn_fused<true><<<BB / 2, 1024, 0, stream>>>(u, rnz, inz, Wt, Winp, Wout,
                                                 yin, states, outputs);
  } else {
    rnn_fused<false><<<BB / 2, 1024, 0, stream>>>(u, rnz, inz, Wrec, Winp, Wout,
                                                  yin, states, outputs);
  }
}

// Round 5
// 63153.113 us; speedup vs baseline: 1.1128x; 1.0586x over previous
//
#include <hip/hip_runtime.h>

// RNN: s_{t+1} = 0.9*s + 0.1*(relu(s@Wrec^T + (u+inz)@Winp^T) + rn)
// d_out = states (B,T,N) fp32 then outputs (B,T,1) fp32, flat-concat.
//
// 64 WGs x 512 threads, 2 batches/WG. R1 shape (proven L2-resident W,
// no spill) + depth-4 register pipeline for the W stream.
// R2/R4 lesson: __launch_bounds__(1024,4) capped VGPR at 64 -> W buffers
// spilled to scratch (WRITE 18GB, FETCH 58GB, 67ms). Here: 512 threads,
// launch_bounds(512,2) -> VGPR cap >=128 under either arg-2 semantics;
// live estimate ~115 -> no spill.
// Phase A: thread (n4, kc) owns 4 n's x 128-wide k-chunk; 32 W4 blocks,
// 4 in flight (wA..wD), last 4 reloads wrap to next step's blocks (W addrs
// t-invariant -> latency hidden across barriers + phase B).
// Phase B: thread n = tid finalizes both batches; fused Wout dot.
// rn loads hoisted one full step ahead.

#define NN 512
#define BB 128
#define TT 1000
#define NIN 6

__global__ void transpose_w(const float* __restrict__ W, float* __restrict__ Wt) {
  __shared__ float tile[32][33];
  const int bx = blockIdx.x * 32, by = blockIdx.y * 32;
  const int tx = threadIdx.x, ty = threadIdx.y;  // 32 x 8
  #pragma unroll
  for (int i = ty; i < 32; i += 8)
    tile[i][tx] = W[(size_t)(by + i) * NN + bx + tx];
  __syncthreads();
  #pragma unroll
  for (int i = ty; i < 32; i += 8)
    Wt[(size_t)(bx + i) * NN + by + tx] = tile[tx][i];
}

__device__ __forceinline__ float wave_sum(float v) {
  #pragma unroll
  for (int off = 32; off > 0; off >>= 1) v += __shfl_xor(v, off, 64);
  return v;
}

// 4 k-rows x 4 n-cols of W, named members (register-resident).
struct W4 {
  float4 e0_, e1_, e2_, e3_;
};

template <bool TRANS>
__device__ __forceinline__ W4 loadw4(const float* __restrict__ wp, int kbase) {
  W4 r;
  if (TRANS) {
    const float* p = wp + (size_t)kbase * NN;  // Wt[k][n]: row k, 4 n's
    r.e0_ = *reinterpret_cast<const float4*>(p);
    r.e1_ = *reinterpret_cast<const float4*>(p + NN);
    r.e2_ = *reinterpret_cast<const float4*>(p + 2 * NN);
    r.e3_ = *reinterpret_cast<const float4*>(p + 3 * NN);
  } else {
    const float* p = wp + kbase;  // W[n][k] gather fallback
    r.e0_.x = p[0*NN+0]; r.e0_.y = p[1*NN+0]; r.e0_.z = p[2*NN+0]; r.e0_.w = p[3*NN+0];
    r.e1_.x = p[0*NN+1]; r.e1_.y = p[1*NN+1]; r.e1_.z = p[2*NN+1]; r.e1_.w = p[3*NN+1];
    r.e2_.x = p[0*NN+2]; r.e2_.y = p[1*NN+2]; r.e2_.z = p[2*NN+2]; r.e2_.w = p[3*NN+2];
    r.e3_.x = p[0*NN+3]; r.e3_.y = p[1*NN+3]; r.e3_.z = p[2*NN+3]; r.e3_.w = p[3*NN+3];
  }
  return r;
}

__device__ __forceinline__ void fma4(float4& a, const float4 w, const float sv) {
  a.x = fmaf(w.x, sv, a.x);
  a.y = fmaf(w.y, sv, a.y);
  a.z = fmaf(w.z, sv, a.z);
  a.w = fmaf(w.w, sv, a.w);
}

// consume one W4 (k..k+3 x 4 n's) against both batches' s broadcasts
__device__ __forceinline__ void consume4(const W4& w4, const float* sp0,
                                         const float* sp1, float4& a0, float4& a1) {
  const float4 s0v = *reinterpret_cast<const float4*>(sp0);
  const float4 s1v = *reinterpret_cast<const float4*>(sp1);
  fma4(a0, w4.e0_, s0v.x); fma4(a1, w4.e0_, s1v.x);
  fma4(a0, w4.e1_, s0v.y); fma4(a1, w4.e1_, s1v.y);
  fma4(a0, w4.e2_, s0v.z); fma4(a1, w4.e2_, s1v.z);
  fma4(a0, w4.e3_, s0v.w); fma4(a1, w4.e3_, s1v.w);
}

template <bool TRANS>
__global__ __launch_bounds__(512, 2)
void rnn_fused(const float* __restrict__ u, const float* __restrict__ rnz,
               const float* __restrict__ inz, const float* __restrict__ Wsrc,
               const float* __restrict__ Winp, const float* __restrict__ Wout,
               const float* __restrict__ yinit,
               float* __restrict__ states, float* __restrict__ outputs) {
  const int tid = threadIdx.x;
  const int n4 = tid & 127;     // phase-A n-group (4 n's), varies per lane
  const int n0 = n4 << 2;
  const int kc = tid >> 7;      // phase-A k-chunk 0..3 (wave-uniform)
  const int kchunk = kc << 7;   // k base (128 wide)
  const int b0 = blockIdx.x * 2;
  const int b1 = b0 + 1;
  const int n  = tid;           // phase-B neuron (both batches)

  __shared__ __align__(16) float s[2][NN];       // 4 KB
  __shared__ __align__(16) float red[2][4][NN];  // 16 KB, [b][kc][n]
  __shared__ float ubuf[2 * NIN];
  __shared__ float outred[2][8];

  float wi[NIN];
  #pragma unroll
  for (int j = 0; j < NIN; ++j) wi[j] = Winp[n * NIN + j];
  const float wo = Wout[n];
  const float yv = yinit[n];

  const float* rp0 = rnz + (size_t)b0 * TT * NN + n;
  const float* rp1 = rnz + (size_t)b1 * TT * NN + n;
  float* sp0 = states + (size_t)b0 * TT * NN + n;
  float* sp1 = states + (size_t)b1 * TT * NN + n;

  // t = 0
  s[0][tid] = yv;
  s[1][tid] = yv;
  sp0[0] = yv;
  sp1[0] = yv;
  {
    float p = wave_sum(yv * wo);
    if ((tid & 63) == 0) outred[0][tid >> 6] = p;
  }
  __syncthreads();
  if (tid < 2) {
    float a = 0.f;
    #pragma unroll
    for (int w = 0; w < 8; ++w) a += outred[0][w];
    outputs[(tid ? b1 : b0) * TT] = a;
  }
  // next outred write is after sync #1 below -> no race with the read above

  const float* wp = TRANS ? (Wsrc + (size_t)kchunk * NN + n0)
                          : (Wsrc + (size_t)n0 * NN + kchunk);

  // depth-4 prologue: k-blocks 0..3 in flight
  W4 wA = loadw4<TRANS>(wp, 0);
  W4 wB = loadw4<TRANS>(wp, 4);
  W4 wC = loadw4<TRANS>(wp, 8);
  W4 wD = loadw4<TRANS>(wp, 12);

  // rn hoisted one step ahead
  float rn0c = rp0[0];
  float rn1c = rp1[0];

  for (int t = 0; t < TT - 1; ++t) {
    // prefetch NEXT step's rn (row t+1 always exists: t+1 <= TT-1)
    const float rn0n = rp0[(size_t)(t + 1) * NN];
    const float rn1n = rp1[(size_t)(t + 1) * NN];
    float uv = 0.f;
    if (tid < 2 * NIN) {
      const int ib = b0 + (tid >= NIN);
      const int j = (tid < NIN) ? tid : tid - NIN;
      const int idx = (ib * TT + t) * NIN + j;
      uv = u[idx] + inz[idx];
    }

    // ---- phase A: 128-wide k-chunk, depth-4 register pipeline ----
    float4 acc0 = make_float4(0.f, 0.f, 0.f, 0.f);
    float4 acc1 = acc0;
    const float* s0 = &s[0][kchunk];
    const float* s1 = &s[1][kchunk];
    consume4(wA, s0 +   0, s1 +   0, acc0, acc1); wA = loadw4<TRANS>(wp,  16);
    consume4(wB, s0 +   4, s1 +   4, acc0, acc1); wB = loadw4<TRANS>(wp,  20);
    consume4(wC, s0 +   8, s1 +   8, acc0, acc1); wC = loadw4<TRANS>(wp,  24);
    consume4(wD, s0 +  12, s1 +  12, acc0, acc1); wD = loadw4<TRANS>(wp,  28);
    consume4(wA, s0 +  16, s1 +  16, acc0, acc1); wA = loadw4<TRANS>(wp,  32);
    consume4(wB, s0 +  20, s1 +  20, acc0, acc1); wB = loadw4<TRANS>(wp,  36);
    consume4(wC, s0 +  24, s1 +  24, acc0, acc1); wC = loadw4<TRANS>(wp,  40);
    consume4(wD, s0 +  28, s1 +  28, acc0, acc1); wD = loadw4<TRANS>(wp,  44);
    consume4(wA, s0 +  32, s1 +  32, acc0, acc1); wA = loadw4<TRANS>(wp,  48);
    consume4(wB, s0 +  36, s1 +  36, acc0, acc1); wB = loadw4<TRANS>(wp,  52);
    consume4(wC, s0 +  40, s1 +  40, acc0, acc1); wC = loadw4<TRANS>(wp,  56);
    consume4(wD, s0 +  44, s1 +  44, acc0, acc1); wD = loadw4<TRANS>(wp,  60);
    consume4(wA, s0 +  48, s1 +  48, acc0, acc1); wA = loadw4<TRANS>(wp,  64);
    consume4(wB, s0 +  52, s1 +  52, acc0, acc1); wB = loadw4<TRANS>(wp,  68);
    consume4(wC, s0 +  56, s1 +  56, acc0, acc1); wC = loadw4<TRANS>(wp,  72);
    consume4(wD, s0 +  60, s1 +  60, acc0, acc1); wD = loadw4<TRANS>(wp,  76);
    consume4(wA, s0 +  64, s1 +  64, acc0, acc1); wA = loadw4<TRANS>(wp,  80);
    consume4(wB, s0 +  68, s1 +  68, acc0, acc1); wB = loadw4<TRANS>(wp,  84);
    consume4(wC, s0 +  72, s1 +  72, acc0, acc1); wC = loadw4<TRANS>(wp,  88);
    consume4(wD, s0 +  76, s1 +  76, acc0, acc1); wD = loadw4<TRANS>(wp,  92);
    consume4(wA, s0 +  80, s1 +  80, acc0, acc1); wA = loadw4<TRANS>(wp,  96);
    consume4(wB, s0 +  84, s1 +  84, acc0, acc1); wB = loadw4<TRANS>(wp, 100);
    consume4(wC, s0 +  88, s1 +  88, acc0, acc1); wC = loadw4<TRANS>(wp, 104);
    consume4(wD, s0 +  92, s1 +  92, acc0, acc1); wD = loadw4<TRANS>(wp, 108);
    consume4(wA, s0 +  96, s1 +  96, acc0, acc1); wA = loadw4<TRANS>(wp, 112);
    consume4(wB, s0 + 100, s1 + 100, acc0, acc1); wB = loadw4<TRANS>(wp, 116);
    consume4(wC, s0 + 104, s1 + 104, acc0, acc1); wC = loadw4<TRANS>(wp, 120);
    consume4(wD, s0 + 108, s1 + 108, acc0, acc1); wD = loadw4<TRANS>(wp, 124);
    consume4(wA, s0 + 112, s1 + 112, acc0, acc1); wA = loadw4<TRANS>(wp,   0);
    consume4(wB, s0 + 116, s1 + 116, acc0, acc1); wB = loadw4<TRANS>(wp,   4);
    consume4(wC, s0 + 120, s1 + 120, acc0, acc1); wC = loadw4<TRANS>(wp,   8);
    consume4(wD, s0 + 124, s1 + 124, acc0, acc1); wD = loadw4<TRANS>(wp,  12);
    // wA..wD now hold next step's blocks 0..3 -> in flight across barriers

    if (tid < 2 * NIN) ubuf[tid] = uv;
    *reinterpret_cast<float4*>(&red[0][kc][n0]) = acc0;
    *reinterpret_cast<float4*>(&red[1][kc][n0]) = acc1;
    __syncthreads();  // #1: red + ubuf visible

    // ---- phase B: finalize n for both batches ----
    float pre0 = (red[0][0][n] + red[0][1][n]) + (red[0][2][n] + red[0][3][n]);
    float pre1 = (red[1][0][n] + red[1][1][n]) + (red[1][2][n] + red[1][3][n]);
    #pragma unroll
    for (int j = 0; j < NIN; ++j) {
      pre0 = fmaf(ubuf[j], wi[j], pre0);
      pre1 = fmaf(ubuf[NIN + j], wi[j], pre1);
    }
    const float sn0 = 0.9f * s[0][n] + 0.1f * (fmaxf(pre0, 0.f) + rn0c);
    const float sn1 = 0.9f * s[1][n] + 0.1f * (fmaxf(pre1, 0.f) + rn1c);
    sp0[(size_t)(t + 1) * NN] = sn0;
    sp1[(size_t)(t + 1) * NN] = sn1;
    s[0][n] = sn0;  // only thread n touches s[.][n] in phase B: safe
    s[1][n] = sn1;
    rn0c = rn0n;
    rn1c = rn1n;
    float p0 = wave_sum(sn0 * wo);
    float p1 = wave_sum(sn1 * wo);
    if ((tid & 63) == 0) {
      outred[0][tid >> 6] = p0;
      outred[1][tid >> 6] = p1;
    }
    __syncthreads();  // #2: s + outred visible; red safe to overwrite
    if (tid < 2) {
      float a = 0.f;
      #pragma unroll
      for (int w = 0; w < 8; ++w) a += outred[tid][w];
      outputs[(tid ? b1 : b0) * TT + t + 1] = a;
    }
  }
}

extern "C" void kernel_launch(void* const* d_in, const int* in_sizes, int n_in,
                              void* d_out, int out_size, void* d_ws, size_t ws_size,
                              hipStream_t stream) {
  const float* u    = (const float*)d_in[0];
  const float* rnz  = (const float*)d_in[1];
  const float* inz  = (const float*)d_in[2];
  const float* Wrec = (const float*)d_in[3];
  const float* Winp = (const float*)d_in[4];
  const float* Wout = (const float*)d_in[5];
  const float* yin  = (const float*)d_in[6];
  float* states  = (float*)d_out;
  float* outputs = states + (size_t)BB * TT * NN;

  const bool use_t = ws_size >= (size_t)NN * NN * sizeof(float);
  if (use_t) {
    float* Wt = (float*)d_ws;
    transpose_w<<<dim3(16, 16), dim3(32, 8), 0, stream>>>(Wrec, Wt);
    rnn_fused<true><<<BB / 2, 512, 0, stream>>>(u, rnz, inz, Wt, Winp, Wout,
                                                yin, states, outputs);
  } else {
    rnn_fused<false><<<BB / 2, 512, 0, stream>>>(u, rnz, inz, Wrec, Winp, Wout,
                                                 yin, states, outputs);
  }
}

// Round 6
// 8157.541 us; speedup vs baseline: 8.6152x; 7.7417x over previous
//
#include <hip/hip_runtime.h>

// RNN: s_{t+1} = 0.9*s + 0.1*(relu(s@Wrec^T + (u+inz)@Winp^T) + rn)
// d_out = states (B,T,N) fp32 then outputs (B,T,1) fp32, flat-concat.
//
// R5 post-mortem established: per-CU load BW (~130-150 GB/s) bounds any
// design that re-streams the 1 MB W every step (floor ~6.8 us/step; R1's
// 8.1 us/step sat there). This kernel keeps W register-resident:
//   - 32 groups x (P=4 WGs); group g owns batches 4g..4g+3.
//   - WG p of group g holds W[n=0..511][k in slice p (128 wide)] in VGPRs
//     (64 VGPR/thread at 1024 threads), loaded once.
//   - Per step: phase A computes k-partials for all n (256 fmaf/thread);
//     partials -> LDS (4-way k-split reduce) -> 8 KB global slot (L2);
//     release flag; spin on 3 peers (agent-scope acquire/release: the
//     compiler emits L2 writeback/invalidate, handling XCD non-coherence);
//     phase C reduces slots for n-slice p (== k-slice p, so each WG's new
//     s-slice is exactly what IT needs next step: no broadcast), applies
//     the update, writes states.
//   - Slots double-buffered by t&1 (WAR-safe: to enter step t+2 a WG must
//     have seen flags>=t+1, which implies peers finished reading step t).
//   - Flags are monotone (=t) and re-initialized to -1 each call by
//     init_flags (in-stream, graph-capture-safe).
// Outputs projection (states @ Wout.T) runs as a separate trivial kernel.
// Co-residency: 128 WGs x 1024 thr, 1 WG/CU -> fits 256 CUs with 2x slack.
// Fallback: proven R1 kernel if ws_size too small for slots+flags.

#define NN 512
#define BB 128
#define TT 1000
#define NIN 6
#define PP 4            // k-slices = WGs per group
#define GG 4            // batches per group
#define BG (BB / GG)    // 32 groups
#define NWG (PP * BG)   // 128 workgroups
#define SLICE (NN / PP) // 128
#define KPER 32         // k per thread
#define KSPLIT (SLICE / KPER)  // 4
#define SLOT_FLOATS (2 * BG * PP * GG * NN)  // 2 MB / 4
#define WS_NEED (SLOT_FLOATS * sizeof(float) + NWG * sizeof(int))

__global__ void init_flags(int* flags) {
  if (threadIdx.x < NWG) flags[threadIdx.x] = -1;
}

__device__ __forceinline__ float wave_sum(float v) {
  #pragma unroll
  for (int off = 32; off > 0; off >>= 1) v += __shfl_xor(v, off, 64);
  return v;
}

__global__ __launch_bounds__(1024, 1)
void rnn_sync(const float* __restrict__ u, const float* __restrict__ rnz,
              const float* __restrict__ inz, const float* __restrict__ Wrec,
              const float* __restrict__ Winp, const float* __restrict__ yinit,
              float* __restrict__ states, float* __restrict__ slots,
              int* __restrict__ flags) {
  const int tid = threadIdx.x;
  // bid remap so a group's 4 WGs share bid%8 (same XCD if round-robin): perf only
  const int m = blockIdx.x >> 3, x = blockIdx.x & 7;
  const int p = m & 3;                  // my k-slice / n-slice
  const int g = ((m >> 2) << 3) + x;    // my group 0..31
  const int n2 = tid & 255;             // n-pair group
  const int ks = tid >> 8;              // k-split 0..3 (wave-uniform)
  const int nA = n2 << 1;               // phase-A rows nA, nA+1
  const int kbase = p * SLICE + ks * KPER;

  __shared__ __align__(16) float s_sl[GG][SLICE];        // 2 KB  s slice, this group's batches
  __shared__ __align__(16) float pred[KSPLIT][GG][NN];   // 32 KB k-split partials
  __shared__ float ubuf[GG][8];
  __shared__ float winp_s[SLICE][NIN];                   // 3 KB

  // ---- one-time: W fragment into registers (rows nA,nA+1 x kbase..+31) ----
  float4 w0[8], w1[8];
  {
    const float* r0 = Wrec + (size_t)nA * NN + kbase;
    const float* r1 = r0 + NN;
    #pragma unroll
    for (int j = 0; j < 8; ++j) {
      w0[j] = *reinterpret_cast<const float4*>(r0 + 4 * j);
      w1[j] = *reinterpret_cast<const float4*>(r1 + 4 * j);
    }
  }
  // one-time: Winp rows for my n-slice
  if (tid < SLICE * NIN) {
    const int nl = tid / NIN, j = tid - nl * NIN;
    winp_s[nl][j] = Winp[(p * SLICE + nl) * NIN + j];
  }
  // one-time: s_0 = y_init; states[.][0][n-slice]
  if (tid < GG * SLICE) {
    const int b = tid >> 7, nl = tid & 127;
    const float yv = yinit[p * SLICE + nl];
    s_sl[b][nl] = yv;
    states[((size_t)(g * GG + b) * TT) * NN + p * SLICE + nl] = yv;
  }
  __syncthreads();

  const int myflag = g * PP + p;

  for (int t = 0; t < TT - 1; ++t) {
    const int par = t & 1;
    // early per-step loads (latency hidden under phase A)
    float rnv = 0.f;
    if (tid < GG * SLICE) {
      const int b = tid >> 7, nl = tid & 127;
      rnv = rnz[((size_t)(g * GG + b) * TT + t) * NN + p * SLICE + nl];
    }
    if (tid < GG * NIN) {
      const int b = tid / NIN, j = tid - b * NIN;
      const size_t idx = ((size_t)(g * GG + b) * TT + t) * NIN + j;
      ubuf[b][j] = u[idx] + inz[idx];
    }

    // ---- phase A: k-partial matvec, W in registers, s broadcast from LDS ----
    float acc0[GG], acc1[GG];
    #pragma unroll
    for (int b = 0; b < GG; ++b) { acc0[b] = 0.f; acc1[b] = 0.f; }
    #pragma unroll
    for (int b = 0; b < GG; ++b) {
      const float4* sp = reinterpret_cast<const float4*>(&s_sl[b][ks * KPER]);
      #pragma unroll
      for (int j = 0; j < 8; ++j) {
        const float4 sv = sp[j];  // wave-uniform address -> LDS broadcast
        acc0[b] = fmaf(w0[j].x, sv.x, acc0[b]);
        acc0[b] = fmaf(w0[j].y, sv.y, acc0[b]);
        acc0[b] = fmaf(w0[j].z, sv.z, acc0[b]);
        acc0[b] = fmaf(w0[j].w, sv.w, acc0[b]);
        acc1[b] = fmaf(w1[j].x, sv.x, acc1[b]);
        acc1[b] = fmaf(w1[j].y, sv.y, acc1[b]);
        acc1[b] = fmaf(w1[j].z, sv.z, acc1[b]);
        acc1[b] = fmaf(w1[j].w, sv.w, acc1[b]);
      }
    }
    #pragma unroll
    for (int b = 0; b < GG; ++b)
      *reinterpret_cast<float2*>(&pred[ks][b][nA]) = make_float2(acc0[b], acc1[b]);
    __syncthreads();  // #1: pred + ubuf ready

    // ---- combine k-splits, publish 8 KB partial to my slot ----
    if (tid < NN) {
      const int n = tid;
      #pragma unroll
      for (int b = 0; b < GG; ++b) {
        const float v = (pred[0][b][n] + pred[1][b][n]) +
                        (pred[2][b][n] + pred[3][b][n]);
        slots[((((size_t)par * BG + g) * PP + p) * GG + b) * NN + n] = v;
      }
    }
    __syncthreads();  // #2: implicit s_waitcnt vmcnt(0) -> stores drained to L2
    if (tid == 0) {
      __hip_atomic_store(&flags[myflag], t, __ATOMIC_RELEASE,
                         __HIP_MEMORY_SCOPE_AGENT);  // L2 writeback (agent)
      #pragma unroll
      for (int q = 0; q < PP; ++q) {
        while (__hip_atomic_load(&flags[g * PP + q], __ATOMIC_ACQUIRE,
                                 __HIP_MEMORY_SCOPE_AGENT) < t)
          __builtin_amdgcn_s_sleep(2);
      }
    }
    __syncthreads();  // #3: all peers' partials visible

    // ---- phase C: reduce my n-slice across the 4 k-slices, state update ----
    if (tid < GG * SLICE) {
      const int b = tid >> 7, nl = tid & 127;
      const int ng = p * SLICE + nl;
      float pre = 0.f;
      #pragma unroll
      for (int q = 0; q < PP; ++q)
        pre += slots[((((size_t)par * BG + g) * PP + q) * GG + b) * NN + ng];
      #pragma unroll
      for (int j = 0; j < NIN; ++j) pre = fmaf(ubuf[b][j], winp_s[nl][j], pre);
      const float so = s_sl[b][nl];
      const float sn = 0.9f * so + 0.1f * (fmaxf(pre, 0.f) + rnv);
      states[((size_t)(g * GG + b) * TT + t + 1) * NN + ng] = sn;
      s_sl[b][nl] = sn;  // exactly the slice this WG needs next step
    }
    __syncthreads();  // #4: s_sl ready for next phase A; pred reusable
  }
}

// outputs[b][t] = dot(states[b][t][:], Wout)  -- one wave per row
__global__ __launch_bounds__(256)
void out_proj(const float* __restrict__ states, const float* __restrict__ Wout,
              float* __restrict__ outputs) {
  const int lane = threadIdx.x & 63;
  const size_t row = (size_t)blockIdx.x * 4 + (threadIdx.x >> 6);
  if (row >= (size_t)BB * TT) return;
  const float* sr = states + row * NN;
  float acc = 0.f;
  #pragma unroll
  for (int h = 0; h < 2; ++h) {
    const float4 sv = *reinterpret_cast<const float4*>(sr + h * 256 + lane * 4);
    const float4 wv = *reinterpret_cast<const float4*>(Wout + h * 256 + lane * 4);
    acc = fmaf(sv.x, wv.x, acc);
    acc = fmaf(sv.y, wv.y, acc);
    acc = fmaf(sv.z, wv.z, acc);
    acc = fmaf(sv.w, wv.w, acc);
  }
  acc = wave_sum(acc);
  if (lane == 0) outputs[row] = acc;
}

// ---------------- fallback: proven R1 kernel (ws too small) ----------------
__global__ void transpose_w(const float* __restrict__ W, float* __restrict__ Wt) {
  __shared__ float tile[32][33];
  const int bx = blockIdx.x * 32, by = blockIdx.y * 32;
  const int tx = threadIdx.x, ty = threadIdx.y;
  #pragma unroll
  for (int i = ty; i < 32; i += 8)
    tile[i][tx] = W[(size_t)(by + i) * NN + bx + tx];
  __syncthreads();
  #pragma unroll
  for (int i = ty; i < 32; i += 8)
    Wt[(size_t)(bx + i) * NN + by + tx] = tile[tx][i];
}

template <bool TRANS>
__global__ __launch_bounds__(512)
void rnn_fused(const float* __restrict__ u, const float* __restrict__ rnz,
               const float* __restrict__ inz, const float* __restrict__ Wsrc,
               const float* __restrict__ Winp, const float* __restrict__ Wout,
               const float* __restrict__ yinit,
               float* __restrict__ states, float* __restrict__ outputs) {
  const int tid = threadIdx.x;
  const int n4 = tid & 127;
  const int kc = tid >> 7;
  const int b0 = blockIdx.x * 2;
  const int b1 = b0 + 1;

  __shared__ __align__(16) float s[2][NN];
  __shared__ __align__(16) float red[2][128][20];
  __shared__ float ubuf[2 * NIN];
  __shared__ float outred[2][8];

  float wi[NIN];
  #pragma unroll
  for (int j = 0; j < NIN; ++j) wi[j] = Winp[tid * NIN + j];
  const float wo = Wout[tid];
  const float yv = yinit[tid];

  s[0][tid] = yv;
  s[1][tid] = yv;
  states[(size_t)(b0 * TT) * NN + tid] = yv;
  states[(size_t)(b1 * TT) * NN + tid] = yv;
  {
    float pzz = wave_sum(yv * wo);
    if ((tid & 63) == 0) outred[0][tid >> 6] = pzz;
  }
  __syncthreads();
  if (tid < 2) {
    float a = 0.f;
    #pragma unroll
    for (int w = 0; w < 8; ++w) a += outred[0][w];
    outputs[(tid ? b1 : b0) * TT] = a;
  }
  __syncthreads();

  for (int t = 0; t < TT - 1; ++t) {
    const float rn0 = rnz[(size_t)(b0 * TT + t) * NN + tid];
    const float rn1 = rnz[(size_t)(b1 * TT + t) * NN + tid];
    float uv = 0.f;
    if (tid < 2 * NIN) {
      const int b = (tid < NIN) ? b0 : b1;
      const int j = (tid < NIN) ? tid : tid - NIN;
      const int idx = (b * TT + t) * NIN + j;
      uv = u[idx] + inz[idx];
    }
    float a0[4] = {0.f, 0.f, 0.f, 0.f};
    float a1[4] = {0.f, 0.f, 0.f, 0.f};
    const int kbase0 = kc * 128;
    #pragma unroll 4
    for (int j4 = 0; j4 < 32; ++j4) {
      const int kb = kbase0 + j4 * 4;
      const float4 s0v = *reinterpret_cast<const float4*>(&s[0][kb]);
      const float4 s1v = *reinterpret_cast<const float4*>(&s[1][kb]);
      const float s0a[4] = {s0v.x, s0v.y, s0v.z, s0v.w};
      const float s1a[4] = {s1v.x, s1v.y, s1v.z, s1v.w};
      #pragma unroll
      for (int jj = 0; jj < 4; ++jj) {
        const int k = kb + jj;
        float4 w;
        if (TRANS) {
          w = *reinterpret_cast<const float4*>(Wsrc + (size_t)k * NN + (n4 << 2));
        } else {
          const float* pw = Wsrc + (size_t)(n4 << 2) * NN + k;
          w.x = pw[0]; w.y = pw[NN]; w.z = pw[2 * NN]; w.w = pw[3 * NN];
        }
        a0[0] = fmaf(w.x, s0a[jj], a0[0]);
        a0[1] = fmaf(w.y, s0a[jj], a0[1]);
        a0[2] = fmaf(w.z, s0a[jj], a0[2]);
        a0[3] = fmaf(w.w, s0a[jj], a0[3]);
        a1[0] = fmaf(w.x, s1a[jj], a1[0]);
        a1[1] = fmaf(w.y, s1a[jj], a1[1]);
        a1[2] = fmaf(w.z, s1a[jj], a1[2]);
        a1[3] = fmaf(w.w, s1a[jj], a1[3]);
      }
    }
    if (tid < 2 * NIN) ubuf[tid] = uv;
    *reinterpret_cast<float4*>(&red[0][n4][kc << 2]) =
        make_float4(a0[0], a0[1], a0[2], a0[3]);
    *reinterpret_cast<float4*>(&red[1][n4][kc << 2]) =
        make_float4(a1[0], a1[1], a1[2], a1[3]);
    __syncthreads();
    const int n = tid;
    const int r = n >> 2, c = n & 3;
    float pre0 = (red[0][r][c] + red[0][r][4 + c]) +
                 (red[0][r][8 + c] + red[0][r][12 + c]);
    float pre1 = (red[1][r][c] + red[1][r][4 + c]) +
                 (red[1][r][8 + c] + red[1][r][12 + c]);
    #pragma unroll
    for (int j = 0; j < NIN; ++j) {
      pre0 = fmaf(ubuf[j], wi[j], pre0);
      pre1 = fmaf(ubuf[NIN + j], wi[j], pre1);
    }
    const float sn0 = 0.9f * s[0][n] + 0.1f * (fmaxf(pre0, 0.f) + rn0);
    const float sn1 = 0.9f * s[1][n] + 0.1f * (fmaxf(pre1, 0.f) + rn1);
    states[(size_t)(b0 * TT + t + 1) * NN + n] = sn0;
    states[(size_t)(b1 * TT + t + 1) * NN + n] = sn1;
    s[0][n] = sn0;
    s[1][n] = sn1;
    float p0 = wave_sum(sn0 * wo);
    float p1 = wave_sum(sn1 * wo);
    if ((tid & 63) == 0) {
      outred[0][tid >> 6] = p0;
      outred[1][tid >> 6] = p1;
    }
    __syncthreads();
    if (tid < 2) {
      float a = 0.f;
      #pragma unroll
      for (int w = 0; w < 8; ++w) a += outred[tid][w];
      outputs[(tid ? b1 : b0) * TT + t + 1] = a;
    }
  }
}

extern "C" void kernel_launch(void* const* d_in, const int* in_sizes, int n_in,
                              void* d_out, int out_size, void* d_ws, size_t ws_size,
                              hipStream_t stream) {
  const float* u    = (const float*)d_in[0];
  const float* rnz  = (const float*)d_in[1];
  const float* inz  = (const float*)d_in[2];
  const float* Wrec = (const float*)d_in[3];
  const float* Winp = (const float*)d_in[4];
  const float* Wout = (const float*)d_in[5];
  const float* yin  = (const float*)d_in[6];
  float* states  = (float*)d_out;
  float* outputs = states + (size_t)BB * TT * NN;

  if (ws_size >= WS_NEED) {
    float* slots = (float*)d_ws;
    int* flags = (int*)((char*)d_ws + SLOT_FLOATS * sizeof(float));
    init_flags<<<1, 128, 0, stream>>>(flags);
    rnn_sync<<<NWG, 1024, 0, stream>>>(u, rnz, inz, Wrec, Winp, yin,
                                       states, slots, flags);
    out_proj<<<(BB * TT + 3) / 4, 256, 0, stream>>>(states, Wout, outputs);
  } else if (ws_size >= (size_t)NN * NN * sizeof(float)) {
    float* Wt = (float*)d_ws;
    transpose_w<<<dim3(16, 16), dim3(32, 8), 0, stream>>>(Wrec, Wt);
    rnn_fused<true><<<BB / 2, 512, 0, stream>>>(u, rnz, inz, Wt, Winp, Wout,
                                                yin, states, outputs);
  } else {
    rnn_fused<false><<<BB / 2, 512, 0, stream>>>(u, rnz, inz, Wrec, Winp, Wout,
                                                 yin, states, outputs);
  }
}

// Round 8
// 7295.824 us; speedup vs baseline: 9.6328x; 1.1181x over previous
//
#include <hip/hip_runtime.h>

// RNN: s_{t+1} = 0.9*s + 0.1*(relu(s@Wrec^T + (u+inz)@Winp^T) + rn)
// d_out = states (B,T,N) fp32 then outputs (B,T,1) fp32, flat-concat.
//
// Resident-W design, attempt 3.
//   R6: compiler re-loaded W from L2 every step (VGPR_Count=64).
//   R7: float4 "+v" pins -> unsupported tied indirect register inputs.
//   Now: SCALAR "+v" pins (16 floats per asm stmt), inside the t-loop ->
//   post-asm values are opaque, can't be rematerialized from memory, and
//   spilling would cost a reload per iteration -> allocator keeps W live.
//   - 32 groups x PP=4 WGs; group g owns batches 4g..4g+3 (GG=4).
//   - WG p holds W[all 512 n][k-slice p (128 wide)] in VGPRs: 128 floats =
//     w[4][8] float4 per thread (512 threads), loaded once.
//   - Phase A: thread (nq, ks) = 4 n x 32 k, s broadcast from LDS,
//     512 fmaf/thread; partials -> LDS pred[ks][b][n].
//   - Combine: thread n sums 4 ks, publishes 8 KB partial to global slot.
//   - Sync: one monotone counter per group; release-add after barrier
//     (barrier drains slot stores; release does L2 writeback for cross-XCD
//     visibility), relaxed spin to PP*(t+1), one acquire.
//   - Phase C: thread (b, nl) reduces 4 peer slots for n-slice p (== its
//     own next-step k-slice: no broadcast), state update, store.
//   - Slots double-buffered by t&1. WAR-safe: writing parity p at step t+2
//     requires passing the spin at t+1, which requires every peer to have
//     published t+1, which happens after its phase-C read of parity p at t.
// out_proj (states @ Wout.T) is a separate trivial kernel.
// Fallback: proven R1 kernel if workspace too small.

#define NN 512
#define BB 128
#define TT 1000
#define NIN 6
#define PP 4                    // k-slices (WGs per group)
#define GG 4                    // batches per group
#define NGRP (BB / GG)          // 32 groups
#define NWG (PP * NGRP)         // 128 workgroups
#define SLICE (NN / PP)         // 128
#define SLOT_FLOATS (2 * NGRP * PP * GG * NN)   // 2 MB / 4 bytes
#define WS_NEED (SLOT_FLOATS * sizeof(float) + NGRP * sizeof(int))

__global__ void init_cnt(int* cnt) {
  if (threadIdx.x < NGRP) cnt[threadIdx.x] = 0;
}

__device__ __forceinline__ float wave_sum(float v) {
  #pragma unroll
  for (int off = 32; off > 0; off >>= 1) v += __shfl_xor(v, off, 64);
  return v;
}

// empty asm with tied SCALAR outputs: values become opaque (non-remat),
// and per-iteration use makes spilling unattractive. 16 operands/stmt.
__device__ __forceinline__ void pin4(float4& a, float4& b, float4& c, float4& d) {
  asm volatile("" : "+v"(a.x), "+v"(a.y), "+v"(a.z), "+v"(a.w),
                    "+v"(b.x), "+v"(b.y), "+v"(b.z), "+v"(b.w),
                    "+v"(c.x), "+v"(c.y), "+v"(c.z), "+v"(c.w),
                    "+v"(d.x), "+v"(d.y), "+v"(d.z), "+v"(d.w));
}

__global__ __launch_bounds__(512, 1)
void rnn_resident(const float* __restrict__ u, const float* __restrict__ rnz,
                  const float* __restrict__ inz, const float* __restrict__ Wrec,
                  const float* __restrict__ Winp, const float* __restrict__ yinit,
                  float* __restrict__ states, float* __restrict__ slots,
                  int* __restrict__ cnt) {
  const int tid = threadIdx.x;
  // bid remap: a group's 4 WGs share bid&7 (likely same XCD) - perf only.
  const int xcd = blockIdx.x & 7;
  const int rest = blockIdx.x >> 3;   // 0..15
  const int p = rest & 3;             // my k-slice / n-slice
  const int gh = rest >> 2;           // 0..3
  const int g = gh * 8 + xcd;         // my group 0..31

  const int nq = tid & 127;           // n-quad: rows n0..n0+3
  const int n0 = nq << 2;
  const int ks = tid >> 7;            // k-split 0..3 (wave-uniform)
  const int k0 = ks << 5;             // local k base (32 wide)
  const int kg = p * SLICE;           // global k base of my slice

  __shared__ __align__(16) float s_sl[GG][SLICE];    // 2 KB: my k-slice of s
  __shared__ __align__(16) float pred[PP][GG][NN];   // 32 KB: ks partials
  __shared__ float winp_s[SLICE][NIN];               // 3 KB
  __shared__ float ubuf[GG][NIN];

  // ---- one-time: W fragment into registers (4 rows x 32 k = 32 float4) ----
  float4 w[4][8];
  #pragma unroll
  for (int i = 0; i < 4; ++i) {
    const float* wr = Wrec + (size_t)(n0 + i) * NN + kg + k0;
    #pragma unroll
    for (int q = 0; q < 8; ++q)
      w[i][q] = *reinterpret_cast<const float4*>(wr + 4 * q);
  }
  // one-time: Winp rows for my n-slice
  for (int i = tid; i < SLICE * NIN; i += 512) {
    const int nl = i / NIN, j = i - nl * NIN;
    winp_s[nl][j] = Winp[(p * SLICE + nl) * NIN + j];
  }
  // one-time: s_0 = y_init; states[.][0][my n-slice]
  {
    const int b = tid >> 7, nl = tid & 127;
    const float yv = yinit[p * SLICE + nl];
    s_sl[b][nl] = yv;
    states[(size_t)(g * GG + b) * TT * NN + p * SLICE + nl] = yv;
  }
  __syncthreads();

  for (int t = 0; t < TT - 1; ++t) {
    const int par = t & 1;

    // pin W live across the loop (see header comment)
    #pragma unroll
    for (int i = 0; i < 4; ++i) {
      pin4(w[i][0], w[i][1], w[i][2], w[i][3]);
      pin4(w[i][4], w[i][5], w[i][6], w[i][7]);
    }

    // early per-step loads (phase-C operands; latency hidden under phase A)
    const int cb = tid >> 7, cnl = tid & 127;
    const int ng = p * SLICE + cnl;
    const float rnv = rnz[((size_t)(g * GG + cb) * TT + t) * NN + ng];
    if (tid < GG * NIN) {
      const int b = tid / NIN, j = tid - b * NIN;
      const size_t idx = ((size_t)(g * GG + b) * TT + t) * NIN + j;
      ubuf[b][j] = u[idx] + inz[idx];
    }

    // ---- phase A: my k-slice partial for all 4 batches (512 fmaf) ----
    float acc[4][GG];
    #pragma unroll
    for (int i = 0; i < 4; ++i)
      #pragma unroll
      for (int b = 0; b < GG; ++b) acc[i][b] = 0.f;
    #pragma unroll
    for (int b = 0; b < GG; ++b) {
      #pragma unroll
      for (int q = 0; q < 8; ++q) {
        const float4 sv =
            *reinterpret_cast<const float4*>(&s_sl[b][k0 + 4 * q]);
        #pragma unroll
        for (int i = 0; i < 4; ++i) {
          acc[i][b] = fmaf(w[i][q].x, sv.x, acc[i][b]);
          acc[i][b] = fmaf(w[i][q].y, sv.y, acc[i][b]);
          acc[i][b] = fmaf(w[i][q].z, sv.z, acc[i][b]);
          acc[i][b] = fmaf(w[i][q].w, sv.w, acc[i][b]);
        }
      }
    }
    #pragma unroll
    for (int b = 0; b < GG; ++b)
      *reinterpret_cast<float4*>(&pred[ks][b][n0]) =
          make_float4(acc[0][b], acc[1][b], acc[2][b], acc[3][b]);
    __syncthreads();  // #1: pred + ubuf visible

    // ---- combine ks-splits, publish 8 KB partial to my slot ----
    {
      const int n = tid;
      float* sb = slots + (((size_t)par * NGRP + g) * PP + p) * GG * NN;
      #pragma unroll
      for (int b = 0; b < GG; ++b) {
        const float v = (pred[0][b][n] + pred[1][b][n]) +
                        (pred[2][b][n] + pred[3][b][n]);
        sb[(size_t)b * NN + n] = v;
      }
    }
    __syncthreads();  // #2: ALL waves' slot stores retired before release
    if (tid == 0) {
      __hip_atomic_fetch_add(&cnt[g], 1, __ATOMIC_RELEASE,
                             __HIP_MEMORY_SCOPE_AGENT);
      const int target = PP * (t + 1);
      while (__hip_atomic_load(&cnt[g], __ATOMIC_RELAXED,
                               __HIP_MEMORY_SCOPE_AGENT) < target)
        __builtin_amdgcn_s_sleep(1);
      (void)__hip_atomic_load(&cnt[g], __ATOMIC_ACQUIRE,
                              __HIP_MEMORY_SCOPE_AGENT);
    }
    __syncthreads();  // #3: peers' partials visible to all threads

    // ---- phase C: reduce my n-slice across 4 k-slices, state update ----
    {
      const float* sb = slots + ((size_t)par * NGRP + g) * PP * GG * NN;
      float pre = 0.f;
      #pragma unroll
      for (int q = 0; q < PP; ++q)
        pre += sb[((size_t)q * GG + cb) * NN + ng];
      #pragma unroll
      for (int j = 0; j < NIN; ++j)
        pre = fmaf(ubuf[cb][j], winp_s[cnl][j], pre);
      const float so = s_sl[cb][cnl];
      const float sn = 0.9f * so + 0.1f * (fmaxf(pre, 0.f) + rnv);
      states[((size_t)(g * GG + cb) * TT + t + 1) * NN + ng] = sn;
      s_sl[cb][cnl] = sn;  // exactly the k-slice this WG needs next step
    }
    __syncthreads();  // #4: s_sl ready; pred reusable
  }
}

// outputs[b][t] = dot(states[b][t][:], Wout) -- one wave per row
__global__ __launch_bounds__(256)
void out_proj(const float* __restrict__ states, const float* __restrict__ Wout,
              float* __restrict__ outputs) {
  const int lane = threadIdx.x & 63;
  const size_t row = (size_t)blockIdx.x * 4 + (threadIdx.x >> 6);
  if (row >= (size_t)BB * TT) return;
  const float* sr = states + row * NN;
  float acc = 0.f;
  #pragma unroll
  for (int h = 0; h < 2; ++h) {
    const float4 sv = *reinterpret_cast<const float4*>(sr + h * 256 + lane * 4);
    const float4 wv = *reinterpret_cast<const float4*>(Wout + h * 256 + lane * 4);
    acc = fmaf(sv.x, wv.x, acc);
    acc = fmaf(sv.y, wv.y, acc);
    acc = fmaf(sv.z, wv.z, acc);
    acc = fmaf(sv.w, wv.w, acc);
  }
  acc = wave_sum(acc);
  if (lane == 0) outputs[row] = acc;
}

// ---------------- fallback: proven R1 kernel (ws too small) ----------------
__global__ void transpose_w(const float* __restrict__ W, float* __restrict__ Wt) {
  __shared__ float tile[32][33];
  const int bx = blockIdx.x * 32, by = blockIdx.y * 32;
  const int tx = threadIdx.x, ty = threadIdx.y;
  #pragma unroll
  for (int i = ty; i < 32; i += 8)
    tile[i][tx] = W[(size_t)(by + i) * NN + bx + tx];
  __syncthreads();
  #pragma unroll
  for (int i = ty; i < 32; i += 8)
    Wt[(size_t)(bx + i) * NN + by + tx] = tile[tx][i];
}

template <bool TRANS>
__global__ __launch_bounds__(512)
void rnn_fused(const float* __restrict__ u, const float* __restrict__ rnz,
               const float* __restrict__ inz, const float* __restrict__ Wsrc,
               const float* __restrict__ Winp, const float* __restrict__ Wout,
               const float* __restrict__ yinit,
               float* __restrict__ states, float* __restrict__ outputs) {
  const int tid = threadIdx.x;
  const int n4 = tid & 127;
  const int kc = tid >> 7;
  const int b0 = blockIdx.x * 2;
  const int b1 = b0 + 1;

  __shared__ __align__(16) float s[2][NN];
  __shared__ __align__(16) float red[2][128][20];
  __shared__ float ubuf[2 * NIN];
  __shared__ float outred[2][8];

  float wi[NIN];
  #pragma unroll
  for (int j = 0; j < NIN; ++j) wi[j] = Winp[tid * NIN + j];
  const float wo = Wout[tid];
  const float yv = yinit[tid];

  s[0][tid] = yv;
  s[1][tid] = yv;
  states[(size_t)(b0 * TT) * NN + tid] = yv;
  states[(size_t)(b1 * TT) * NN + tid] = yv;
  {
    float pzz = wave_sum(yv * wo);
    if ((tid & 63) == 0) outred[0][tid >> 6] = pzz;
  }
  __syncthreads();
  if (tid < 2) {
    float a = 0.f;
    #pragma unroll
    for (int wq = 0; wq < 8; ++wq) a += outred[0][wq];
    outputs[(tid ? b1 : b0) * TT] = a;
  }
  __syncthreads();

  for (int t = 0; t < TT - 1; ++t) {
    const float rn0 = rnz[(size_t)(b0 * TT + t) * NN + tid];
    const float rn1 = rnz[(size_t)(b1 * TT + t) * NN + tid];
    float uv = 0.f;
    if (tid < 2 * NIN) {
      const int b = (tid < NIN) ? b0 : b1;
      const int j = (tid < NIN) ? tid : tid - NIN;
      const int idx = (b * TT + t) * NIN + j;
      uv = u[idx] + inz[idx];
    }
    float a0[4] = {0.f, 0.f, 0.f, 0.f};
    float a1[4] = {0.f, 0.f, 0.f, 0.f};
    const int kbase0 = kc * 128;
    #pragma unroll 4
    for (int j4 = 0; j4 < 32; ++j4) {
      const int kb = kbase0 + j4 * 4;
      const float4 s0v = *reinterpret_cast<const float4*>(&s[0][kb]);
      const float4 s1v = *reinterpret_cast<const float4*>(&s[1][kb]);
      const float s0a[4] = {s0v.x, s0v.y, s0v.z, s0v.w};
      const float s1a[4] = {s1v.x, s1v.y, s1v.z, s1v.w};
      #pragma unroll
      for (int jj = 0; jj < 4; ++jj) {
        const int k = kb + jj;
        float4 wv;
        if (TRANS) {
          wv = *reinterpret_cast<const float4*>(Wsrc + (size_t)k * NN + (n4 << 2));
        } else {
          const float* pw = Wsrc + (size_t)(n4 << 2) * NN + k;
          wv.x = pw[0]; wv.y = pw[NN]; wv.z = pw[2 * NN]; wv.w = pw[3 * NN];
        }
        a0[0] = fmaf(wv.x, s0a[jj], a0[0]);
        a0[1] = fmaf(wv.y, s0a[jj], a0[1]);
        a0[2] = fmaf(wv.z, s0a[jj], a0[2]);
        a0[3] = fmaf(wv.w, s0a[jj], a0[3]);
        a1[0] = fmaf(wv.x, s1a[jj], a1[0]);
        a1[1] = fmaf(wv.y, s1a[jj], a1[1]);
        a1[2] = fmaf(wv.z, s1a[jj], a1[2]);
        a1[3] = fmaf(wv.w, s1a[jj], a1[3]);
      }
    }
    if (tid < 2 * NIN) ubuf[tid] = uv;
    *reinterpret_cast<float4*>(&red[0][n4][kc << 2]) =
        make_float4(a0[0], a0[1], a0[2], a0[3]);
    *reinterpret_cast<float4*>(&red[1][n4][kc << 2]) =
        make_float4(a1[0], a1[1], a1[2], a1[3]);
    __syncthreads();
    const int n = tid;
    const int r = n >> 2, c = n & 3;
    float pre0 = (red[0][r][c] + red[0][r][4 + c]) +
                 (red[0][r][8 + c] + red[0][r][12 + c]);
    float pre1 = (red[1][r][c] + red[1][r][4 + c]) +
                 (red[1][r][8 + c] + red[1][r][12 + c]);
    #pragma unroll
    for (int j = 0; j < NIN; ++j) {
      pre0 = fmaf(ubuf[j], wi[j], pre0);
      pre1 = fmaf(ubuf[NIN + j], wi[j], pre1);
    }
    const float sn0 = 0.9f * s[0][n] + 0.1f * (fmaxf(pre0, 0.f) + rn0);
    const float sn1 = 0.9f * s[1][n] + 0.1f * (fmaxf(pre1, 0.f) + rn1);
    states[(size_t)(b0 * TT + t + 1) * NN + n] = sn0;
    states[(size_t)(b1 * TT + t + 1) * NN + n] = sn1;
    s[0][n] = sn0;
    s[1][n] = sn1;
    float p0 = wave_sum(sn0 * wo);
    float p1 = wave_sum(sn1 * wo);
    if ((tid & 63) == 0) {
      outred[0][tid >> 6] = p0;
      outred[1][tid >> 6] = p1;
    }
    __syncthreads();
    if (tid < 2) {
      float a = 0.f;
      #pragma unroll
      for (int wq = 0; wq < 8; ++wq) a += outred[tid][wq];
      outputs[(tid ? b1 : b0) * TT + t + 1] = a;
    }
  }
}

extern "C" void kernel_launch(void* const* d_in, const int* in_sizes, int n_in,
                              void* d_out, int out_size, void* d_ws, size_t ws_size,
                              hipStream_t stream) {
  const float* u    = (const float*)d_in[0];
  const float* rnz  = (const float*)d_in[1];
  const float* inz  = (const float*)d_in[2];
  const float* Wrec = (const float*)d_in[3];
  const float* Winp = (const float*)d_in[4];
  const float* Wout = (const float*)d_in[5];
  const float* yin  = (const float*)d_in[6];
  float* states  = (float*)d_out;
  float* outputs = states + (size_t)BB * TT * NN;

  if (ws_size >= WS_NEED) {
    float* slots = (float*)d_ws;
    int* cnt = (int*)((char*)d_ws + SLOT_FLOATS * sizeof(float));
    init_cnt<<<1, 64, 0, stream>>>(cnt);
    rnn_resident<<<NWG, 512, 0, stream>>>(u, rnz, inz, Wrec, Winp, yin,
                                          states, slots, cnt);
    out_proj<<<(BB * TT + 3) / 4, 256, 0, stream>>>(states, Wout, outputs);
  } else if (ws_size >= (size_t)NN * NN * sizeof(float)) {
    float* Wt = (float*)d_ws;
    transpose_w<<<dim3(16, 16), dim3(32, 8), 0, stream>>>(Wrec, Wt);
    rnn_fused<true><<<BB / 2, 512, 0, stream>>>(u, rnz, inz, Wt, Winp, Wout,
                                                yin, states, outputs);
  } else {
    rnn_fused<false><<<BB / 2, 512, 0, stream>>>(u, rnz, inz, Wrec, Winp, Wout,
                                                 yin, states, outputs);
  }
}

// Round 9
// 4058.801 us; speedup vs baseline: 17.3152x; 1.7975x over previous
//
#include <hip/hip_runtime.h>

// RNN: s_{t+1} = 0.9*s + 0.1*(relu(s@Wrec^T + (u+inz)@Winp^T) + rn)
// d_out = states (B,T,N) fp32 then outputs (B,T,1) fp32, flat-concat.
//
// Resident-W, n-partitioned, IF-synced (R9).
//   R8 lesson: agent-scope release/acquire emit buffer_wbl2/buffer_inv;
//   16 WGs/XCD x 999 steps invalidate the shared L2 -> everything at IF
//   latency, ~6 us/step of sync. Here NO cache maintenance at all:
//   exchanged data moves via system-scope RELAXED atomics (sc0sc1 ->
//   bypass L1/L2, served by the chip-coherent Infinity Cache). Every
//   exchanged address is written once and read once (states[t+1] rows),
//   so there is no stale-line hazard; L2 keeps serving rnz/u streams.
//   - 32 groups x PP=4 WGs; group g owns batches 4g..4g+3 (GG=4).
//   - WG p owns n-slice p: W[p*128..+128)[all 512 k] in VGPRs
//     (128 floats/thread = w[4][8] float4), pinned by scalar asm "+v".
//   - Phase A: thread (nq,ks) = 4 n x 32 k x 4 b, s broadcast from LDS
//     (1 float4 s-read per 16 fmaf; ks=tid>>5 -> 2 addrs/wave = free
//     2-way); partials -> pred[16][4][128] LDS.
//   - Update (thread = (b,nl)): reduce 16 k-splits, + Winp dot, state
//     update; store new s to states[t+1] (system relaxed = payload) and
//     to LDS s_all.
//   - Sync: __syncthreads (drains vmcnt -> payload at IF), tid0 stores
//     flag=t+1 (system relaxed), spins on 3 peer flags, barrier, then
//     all threads fetch peer slices from states[t+1] (system relaxed)
//     into s_all. The exchange medium IS the output array.
// out_proj (states @ Wout.T) is a separate trivial kernel.
// Fallback: proven R1 kernel if workspace too small (needs 512 B).

#define NN 512
#define BB 128
#define TT 1000
#define NIN 6
#define PP 4                    // n-slices (WGs per group)
#define GG 4                    // batches per group
#define NGRP (BB / GG)          // 32 groups
#define NWG (PP * NGRP)         // 128 workgroups
#define SLICE (NN / PP)         // 128
#define WS_NEED (NWG * sizeof(int))

__global__ void init_flags(int* flags) {
  if (threadIdx.x < NWG) flags[threadIdx.x] = 0;
}

__device__ __forceinline__ float wave_sum(float v) {
  #pragma unroll
  for (int off = 32; off > 0; off >>= 1) v += __shfl_xor(v, off, 64);
  return v;
}

// empty asm with tied SCALAR outputs: values become opaque (non-remat).
__device__ __forceinline__ void pin4(float4& a, float4& b, float4& c, float4& d) {
  asm volatile("" : "+v"(a.x), "+v"(a.y), "+v"(a.z), "+v"(a.w),
                    "+v"(b.x), "+v"(b.y), "+v"(b.z), "+v"(b.w),
                    "+v"(c.x), "+v"(c.y), "+v"(c.z), "+v"(c.w),
                    "+v"(d.x), "+v"(d.y), "+v"(d.z), "+v"(d.w));
}

__global__ __launch_bounds__(512, 1)
void rnn_nsplit(const float* __restrict__ u, const float* __restrict__ rnz,
                const float* __restrict__ inz, const float* __restrict__ Wrec,
                const float* __restrict__ Winp, const float* __restrict__ yinit,
                float* __restrict__ states, int* __restrict__ flags) {
  const int tid = threadIdx.x;
  // bid remap: a group's 4 WGs share bid&7 (likely same XCD) - perf only.
  const int xcd = blockIdx.x & 7;
  const int rest = blockIdx.x >> 3;   // 0..15
  const int p = rest & 3;             // my n-slice
  const int g = (rest >> 2) * 8 + xcd;  // my group 0..31

  // phase-A mapping: 4 n-rows x 32 k x 4 batches per thread
  const int nq = tid & 31;            // n-quad index within slice
  const int n0 = nq << 2;             // local n base (4 rows)
  const int ks = tid >> 5;            // k-split 0..15 (2 values per wave)
  const int k0 = ks << 5;             // k base (32 wide)
  // update/fetch mapping: (batch, local n)
  const int ub = tid >> 7;            // batch 0..3
  const int un = tid & 127;           // local n
  const int ung = p * SLICE + un;     // global n

  __shared__ __align__(16) float s_all[GG][NN];         // 8 KB: full s
  __shared__ __align__(16) float pred[16][GG][SLICE];   // 32 KB
  __shared__ float winp_s[SLICE][NIN];                  // 3 KB
  __shared__ float ubuf[GG][NIN];

  // ---- one-time: W fragment (4 rows x 32 k = 32 float4) ----
  float4 w[4][8];
  #pragma unroll
  for (int i = 0; i < 4; ++i) {
    const float* wr = Wrec + (size_t)(p * SLICE + n0 + i) * NN + k0;
    #pragma unroll
    for (int q = 0; q < 8; ++q)
      w[i][q] = *reinterpret_cast<const float4*>(wr + 4 * q);
  }
  // one-time: Winp rows for my n-slice
  for (int i = tid; i < SLICE * NIN; i += 512) {
    const int r = i / NIN, j = i - r * NIN;
    winp_s[r][j] = Winp[(p * SLICE + r) * NIN + j];
  }
  // one-time: full s_0 from y_init; states row 0 (my slice, plain store)
  for (int i = tid; i < GG * NN; i += 512)
    s_all[i >> 9][i & 511] = yinit[i & 511];
  states[(size_t)(g * GG + ub) * TT * NN + ung] = yinit[ung];
  __syncthreads();

  const int myflag = g * PP + p;

  for (int t = 0; t < TT - 1; ++t) {
    // pin W live across the loop (R6: unpinned W was re-loaded from L2)
    #pragma unroll
    for (int i = 0; i < 4; ++i) {
      pin4(w[i][0], w[i][1], w[i][2], w[i][3]);
      pin4(w[i][4], w[i][5], w[i][6], w[i][7]);
    }

    // early per-step loads (plain, L2-cached; used after barrier #1)
    const float rnv = rnz[((size_t)(g * GG + ub) * TT + t) * NN + ung];
    if (tid < GG * NIN) {
      const int b = tid / NIN, j = tid - b * NIN;
      const size_t idx = ((size_t)(g * GG + b) * TT + t) * NIN + j;
      ubuf[b][j] = u[idx] + inz[idx];
    }

    // ---- phase A: 4 n x 32 k x 4 b partial dots (512 fmaf) ----
    float a0[4], a1[4], a2[4], a3[4];  // [batch] for rows n0..n0+3
    #pragma unroll
    for (int b = 0; b < GG; ++b) { a0[b] = 0.f; a1[b] = 0.f; a2[b] = 0.f; a3[b] = 0.f; }
    #pragma unroll
    for (int b = 0; b < GG; ++b) {
      #pragma unroll
      for (int q = 0; q < 8; ++q) {
        const float4 sv = *reinterpret_cast<const float4*>(&s_all[b][k0 + 4 * q]);
        a0[b] = fmaf(w[0][q].x, sv.x, a0[b]);
        a0[b] = fmaf(w[0][q].y, sv.y, a0[b]);
        a0[b] = fmaf(w[0][q].z, sv.z, a0[b]);
        a0[b] = fmaf(w[0][q].w, sv.w, a0[b]);
        a1[b] = fmaf(w[1][q].x, sv.x, a1[b]);
        a1[b] = fmaf(w[1][q].y, sv.y, a1[b]);
        a1[b] = fmaf(w[1][q].z, sv.z, a1[b]);
        a1[b] = fmaf(w[1][q].w, sv.w, a1[b]);
        a2[b] = fmaf(w[2][q].x, sv.x, a2[b]);
        a2[b] = fmaf(w[2][q].y, sv.y, a2[b]);
        a2[b] = fmaf(w[2][q].z, sv.z, a2[b]);
        a2[b] = fmaf(w[2][q].w, sv.w, a2[b]);
        a3[b] = fmaf(w[3][q].x, sv.x, a3[b]);
        a3[b] = fmaf(w[3][q].y, sv.y, a3[b]);
        a3[b] = fmaf(w[3][q].z, sv.z, a3[b]);
        a3[b] = fmaf(w[3][q].w, sv.w, a3[b]);
      }
      *reinterpret_cast<float4*>(&pred[ks][b][n0]) =
          make_float4(a0[b], a1[b], a2[b], a3[b]);
    }
    __syncthreads();  // #1: pred + ubuf visible

    // ---- update: thread (ub, un) finalizes one (batch, n) ----
    float sn;
    {
      float pre = 0.f;
      #pragma unroll
      for (int q = 0; q < 16; ++q) pre += pred[q][ub][un];
      #pragma unroll
      for (int j = 0; j < NIN; ++j) pre = fmaf(ubuf[ub][j], winp_s[un][j], pre);
      const float so = s_all[ub][ung];
      sn = 0.9f * so + 0.1f * (fmaxf(pre, 0.f) + rnv);
      // payload: system-scope relaxed -> sc0sc1, straight to IF (coherent)
      __hip_atomic_store(&states[((size_t)(g * GG + ub) * TT + t + 1) * NN + ung],
                         sn, __ATOMIC_RELAXED, __HIP_MEMORY_SCOPE_SYSTEM);
      s_all[ub][ung] = sn;
    }
    __syncthreads();  // #2: vmcnt(0) before barrier -> payload at IF; LDS too
    if (tid == 0) {
      __hip_atomic_store(&flags[myflag], t + 1, __ATOMIC_RELAXED,
                         __HIP_MEMORY_SCOPE_SYSTEM);
      #pragma unroll
      for (int q = 0; q < PP; ++q) {
        if (q == p) continue;
        while (__hip_atomic_load(&flags[g * PP + q], __ATOMIC_RELAXED,
                                 __HIP_MEMORY_SCOPE_SYSTEM) < t + 1)
          __builtin_amdgcn_s_sleep(1);
      }
    }
    __syncthreads();  // #3: peers published

    // ---- fetch 3 peer slices (system relaxed, from IF) into s_all ----
    #pragma unroll
    for (int i = 0; i < 3; ++i) {
      const int q = (p + 1 + i) & 3;
      const float v = __hip_atomic_load(
          &states[((size_t)(g * GG + ub) * TT + t + 1) * NN + q * SLICE + un],
          __ATOMIC_RELAXED, __HIP_MEMORY_SCOPE_SYSTEM);
      s_all[ub][q * SLICE + un] = v;
    }
    __syncthreads();  // #4: s_all complete for next phase A
  }
}

// outputs[b][t] = dot(states[b][t][:], Wout) -- one wave per row
__global__ __launch_bounds__(256)
void out_proj(const float* __restrict__ states, const float* __restrict__ Wout,
              float* __restrict__ outputs) {
  const int lane = threadIdx.x & 63;
  const size_t row = (size_t)blockIdx.x * 4 + (threadIdx.x >> 6);
  if (row >= (size_t)BB * TT) return;
  const float* sr = states + row * NN;
  float acc = 0.f;
  #pragma unroll
  for (int h = 0; h < 2; ++h) {
    const float4 sv = *reinterpret_cast<const float4*>(sr + h * 256 + lane * 4);
    const float4 wv = *reinterpret_cast<const float4*>(Wout + h * 256 + lane * 4);
    acc = fmaf(sv.x, wv.x, acc);
    acc = fmaf(sv.y, wv.y, acc);
    acc = fmaf(sv.z, wv.z, acc);
    acc = fmaf(sv.w, wv.w, acc);
  }
  acc = wave_sum(acc);
  if (lane == 0) outputs[row] = acc;
}

// ---------------- fallback: proven R1 kernel (ws too small) ----------------
template <bool TRANS>
__global__ __launch_bounds__(512)
void rnn_fused(const float* __restrict__ u, const float* __restrict__ rnz,
               const float* __restrict__ inz, const float* __restrict__ Wsrc,
               const float* __restrict__ Winp, const float* __restrict__ Wout,
               const float* __restrict__ yinit,
               float* __restrict__ states, float* __restrict__ outputs) {
  const int tid = threadIdx.x;
  const int n4 = tid & 127;
  const int kc = tid >> 7;
  const int b0 = blockIdx.x * 2;
  const int b1 = b0 + 1;

  __shared__ __align__(16) float s[2][NN];
  __shared__ __align__(16) float red[2][128][20];
  __shared__ float ubuf[2 * NIN];
  __shared__ float outred[2][8];

  float wi[NIN];
  #pragma unroll
  for (int j = 0; j < NIN; ++j) wi[j] = Winp[tid * NIN + j];
  const float wo = Wout[tid];
  const float yv = yinit[tid];

  s[0][tid] = yv;
  s[1][tid] = yv;
  states[(size_t)(b0 * TT) * NN + tid] = yv;
  states[(size_t)(b1 * TT) * NN + tid] = yv;
  {
    float pzz = wave_sum(yv * wo);
    if ((tid & 63) == 0) outred[0][tid >> 6] = pzz;
  }
  __syncthreads();
  if (tid < 2) {
    float a = 0.f;
    #pragma unroll
    for (int wq = 0; wq < 8; ++wq) a += outred[0][wq];
    outputs[(tid ? b1 : b0) * TT] = a;
  }
  __syncthreads();

  for (int t = 0; t < TT - 1; ++t) {
    const float rn0 = rnz[(size_t)(b0 * TT + t) * NN + tid];
    const float rn1 = rnz[(size_t)(b1 * TT + t) * NN + tid];
    float uv = 0.f;
    if (tid < 2 * NIN) {
      const int b = (tid < NIN) ? b0 : b1;
      const int j = (tid < NIN) ? tid : tid - NIN;
      const int idx = (b * TT + t) * NIN + j;
      uv = u[idx] + inz[idx];
    }
    float a0[4] = {0.f, 0.f, 0.f, 0.f};
    float a1[4] = {0.f, 0.f, 0.f, 0.f};
    const int kbase0 = kc * 128;
    #pragma unroll 4
    for (int j4 = 0; j4 < 32; ++j4) {
      const int kb = kbase0 + j4 * 4;
      const float4 s0v = *reinterpret_cast<const float4*>(&s[0][kb]);
      const float4 s1v = *reinterpret_cast<const float4*>(&s[1][kb]);
      const float s0a[4] = {s0v.x, s0v.y, s0v.z, s0v.w};
      const float s1a[4] = {s1v.x, s1v.y, s1v.z, s1v.w};
      #pragma unroll
      for (int jj = 0; jj < 4; ++jj) {
        const int k = kb + jj;
        float4 wv;
        if (TRANS) {
          wv = *reinterpret_cast<const float4*>(Wsrc + (size_t)k * NN + (n4 << 2));
        } else {
          const float* pw = Wsrc + (size_t)(n4 << 2) * NN + k;
          wv.x = pw[0]; wv.y = pw[NN]; wv.z = pw[2 * NN]; wv.w = pw[3 * NN];
        }
        a0[0] = fmaf(wv.x, s0a[jj], a0[0]);
        a0[1] = fmaf(wv.y, s0a[jj], a0[1]);
        a0[2] = fmaf(wv.z, s0a[jj], a0[2]);
        a0[3] = fmaf(wv.w, s0a[jj], a0[3]);
        a1[0] = fmaf(wv.x, s1a[jj], a1[0]);
        a1[1] = fmaf(wv.y, s1a[jj], a1[1]);
        a1[2] = fmaf(wv.z, s1a[jj], a1[2]);
        a1[3] = fmaf(wv.w, s1a[jj], a1[3]);
      }
    }
    if (tid < 2 * NIN) ubuf[tid] = uv;
    *reinterpret_cast<float4*>(&red[0][n4][kc << 2]) =
        make_float4(a0[0], a0[1], a0[2], a0[3]);
    *reinterpret_cast<float4*>(&red[1][n4][kc << 2]) =
        make_float4(a1[0], a1[1], a1[2], a1[3]);
    __syncthreads();
    const int n = tid;
    const int r = n >> 2, c = n & 3;
    float pre0 = (red[0][r][c] + red[0][r][4 + c]) +
                 (red[0][r][8 + c] + red[0][r][12 + c]);
    float pre1 = (red[1][r][c] + red[1][r][4 + c]) +
                 (red[1][r][8 + c] + red[1][r][12 + c]);
    #pragma unroll
    for (int j = 0; j < NIN; ++j) {
      pre0 = fmaf(ubuf[j], wi[j], pre0);
      pre1 = fmaf(ubuf[NIN + j], wi[j], pre1);
    }
    const float sn0 = 0.9f * s[0][n] + 0.1f * (fmaxf(pre0, 0.f) + rn0);
    const float sn1 = 0.9f * s[1][n] + 0.1f * (fmaxf(pre1, 0.f) + rn1);
    states[(size_t)(b0 * TT + t + 1) * NN + n] = sn0;
    states[(size_t)(b1 * TT + t + 1) * NN + n] = sn1;
    s[0][n] = sn0;
    s[1][n] = sn1;
    float p0 = wave_sum(sn0 * wo);
    float p1 = wave_sum(sn1 * wo);
    if ((tid & 63) == 0) {
      outred[0][tid >> 6] = p0;
      outred[1][tid >> 6] = p1;
    }
    __syncthreads();
    if (tid < 2) {
      float a = 0.f;
      #pragma unroll
      for (int wq = 0; wq < 8; ++wq) a += outred[tid][wq];
      outputs[(tid ? b1 : b0) * TT + t + 1] = a;
    }
  }
}

extern "C" void kernel_launch(void* const* d_in, const int* in_sizes, int n_in,
                              void* d_out, int out_size, void* d_ws, size_t ws_size,
                              hipStream_t stream) {
  const float* u    = (const float*)d_in[0];
  const float* rnz  = (const float*)d_in[1];
  const float* inz  = (const float*)d_in[2];
  const float* Wrec = (const float*)d_in[3];
  const float* Winp = (const float*)d_in[4];
  const float* Wout = (const float*)d_in[5];
  const float* yin  = (const float*)d_in[6];
  float* states  = (float*)d_out;
  float* outputs = states + (size_t)BB * TT * NN;

  if (ws_size >= WS_NEED) {
    int* flags = (int*)d_ws;
    init_flags<<<1, 128, 0, stream>>>(flags);
    rnn_nsplit<<<NWG, 512, 0, stream>>>(u, rnz, inz, Wrec, Winp, yin,
                                        states, flags);
    out_proj<<<(BB * TT + 3) / 4, 256, 0, stream>>>(states, Wout, outputs);
  } else {
    rnn_fused<false><<<BB / 2, 512, 0, stream>>>(u, rnz, inz, Wrec, Winp, Wout,
                                                 yin, states, outputs);
  }
}